// Round 2
// baseline (308.038 us; speedup 1.0000x reference)
//
#include <hip/hip_runtime.h>

#define HD 64      // hidden/feature dim (D == H == 64)
#define PSUB 16    // partial slots per graph (pool accumulation spread)
#define NBLK 256   // histogram blocks (edge slices)
#define LOG_NBLK 8
#define NBKT 512   // dst buckets (bucket = dst >> 7, 128 nodes each; N <= 65536)

// ---- bf16 helpers (manual, RNE) ----
__device__ __forceinline__ unsigned short f2bf(float f) {
    union { float f; unsigned u; } v; v.f = f;
    unsigned r = v.u + 0x7FFF + ((v.u >> 16) & 1);
    return (unsigned short)(r >> 16);
}
__device__ __forceinline__ float bf2f(unsigned short h) {
    union { unsigned u; float f; } v; v.u = ((unsigned)h) << 16;
    return v.f;
}
__device__ __forceinline__ int rdlane(int v, int l) {
    return __builtin_amdgcn_readlane(v, l);
}

// ================= atomic-free bucketed CSR build =================

__global__ __launch_bounds__(256) void hist1_k(const int* __restrict__ dst,
                                               int* __restrict__ hist, int E, int chunk)
{
    __shared__ int lh[NBKT];
    int t = threadIdx.x;
    for (int i = t; i < NBKT; i += 256) lh[i] = 0;
    __syncthreads();
    int base = blockIdx.x * chunk;
    int end  = min(base + chunk, E);
    for (int i = base + t; i < end; i += 256)
        atomicAdd(&lh[dst[i] >> 7], 1);
    __syncthreads();
    for (int i = t; i < NBKT; i += 256)
        hist[blockIdx.x * NBKT + i] = lh[i];
}

// 2a) tile-reduce logical order l = bkt*NBLK + blk  (phys = blk*NBKT + bkt)
__global__ __launch_bounds__(256) void scanA_k(const int* __restrict__ hist,
                                               int* __restrict__ tsum)
{
    __shared__ int s[256];
    int t = threadIdx.x;
    int l = blockIdx.x * 256 + t;
    int phys = (l & (NBLK - 1)) * NBKT + (l >> LOG_NBLK);
    s[t] = hist[phys];
    __syncthreads();
    for (int off = 128; off > 0; off >>= 1) {
        if (t < off) s[t] += s[t + off];
        __syncthreads();
    }
    if (t == 0) tsum[blockIdx.x] = s[0];
}

// 2b) single block: exclusive-scan tsum; compute gstart; zero partial
__global__ __launch_bounds__(1024) void scanB_k(int* __restrict__ tsum, int nb,
    const int* __restrict__ batch, int* __restrict__ gstart, int n, int G,
    float* __restrict__ partial, int psz)
{
    __shared__ int s[1024];
    int t = threadIdx.x;
    int v = (t < nb) ? tsum[t] : 0;
    s[t] = v;
    __syncthreads();
    for (int off = 1; off < 1024; off <<= 1) {
        int u = (t >= off) ? s[t - off] : 0;
        __syncthreads();
        s[t] += u;
        __syncthreads();
    }
    if (t < nb) tsum[t] = s[t] - v;
    if (t <= G) {
        if (t == G) gstart[t] = n;
        else {
            int lo = 0, hi = n;
            while (lo < hi) { int m = (lo + hi) >> 1; if (batch[m] < t) lo = m + 1; else hi = m; }
            gstart[t] = lo;
        }
    }
    for (int i = t; i < psz; i += 1024) partial[i] = 0.f;
}

__global__ __launch_bounds__(256) void scanC_k(const int* __restrict__ hist,
                                               const int* __restrict__ tsum,
                                               int* __restrict__ scanned)
{
    __shared__ int s[256];
    int t = threadIdx.x;
    int l = blockIdx.x * 256 + t;
    int phys = (l & (NBLK - 1)) * NBKT + (l >> LOG_NBLK);
    int own = hist[phys];
    s[t] = own;
    __syncthreads();
    for (int off = 1; off < 256; off <<= 1) {
        int u = (t >= off) ? s[t - off] : 0;
        __syncthreads();
        s[t] += u;
        __syncthreads();
    }
    scanned[l] = tsum[blockIdx.x] + s[t] - own;
}

// 3) bucket-sorted append of packed (src<<7 | dst&127); per-block private ranges
__global__ __launch_bounds__(256) void append_k(const int* __restrict__ src,
    const int* __restrict__ dst, const int* __restrict__ scanned,
    int* __restrict__ pairs, int E, int chunk)
{
    __shared__ int cur[NBKT];
    int t = threadIdx.x;
    int blk = blockIdx.x;
    for (int i = t; i < NBKT; i += 256) cur[i] = scanned[i * NBLK + blk];
    __syncthreads();
    int base = blk * chunk;
    int end  = min(base + chunk, E);
    for (int i = base + t; i < end; i += 256) {
        int s = src[i], d = dst[i];
        int p = atomicAdd(&cur[d >> 7], 1);
        pairs[p] = (s << 7) | (d & 127);
    }
}

// 4) per-bucket: node counts -> offsets/dis, then in-bucket scatter of csr_src
__global__ __launch_bounds__(256) void bucket_csr_k(const int* __restrict__ pairs,
    const int* __restrict__ scanned, int* __restrict__ offsets,
    float* __restrict__ dis, int* __restrict__ csr_src, int N, int E)
{
    __shared__ int cnt[128];
    __shared__ int sc[128];
    __shared__ int cur[128];
    int t = threadIdx.x;
    int b = blockIdx.x;
    int nodeBase = b * 128;
    int nNodes = min(128, N - nodeBase);
    int bBase = scanned[b * NBLK];
    int bEnd  = (b + 1 < NBKT) ? scanned[(b + 1) * NBLK] : E;

    if (t < 128) cnt[t] = 0;
    __syncthreads();
    for (int i = bBase + t; i < bEnd; i += 256)
        atomicAdd(&cnt[pairs[i] & 127], 1);
    __syncthreads();
    int myc = (t < 128) ? cnt[t] : 0;
    if (t < 128) sc[t] = myc;
    __syncthreads();
    for (int off = 1; off < 128; off <<= 1) {
        int u = (t < 128 && t >= off) ? sc[t - off] : 0;
        __syncthreads();
        if (t < 128) sc[t] += u;
        __syncthreads();
    }
    if (t < 128) {
        int excl = sc[t] - myc;
        cur[t] = excl;
        if (t < nNodes) {
            offsets[nodeBase + t] = bBase + excl;
            dis[nodeBase + t] = rsqrtf(1.0f + (float)myc);
        }
    }
    if (t == 0 && b == gridDim.x - 1) offsets[N] = E;
    __syncthreads();
    for (int i = bBase + t; i < bEnd; i += 256) {
        int pk = pairs[i];
        int pos = bBase + atomicAdd(&cur[pk & 127], 1);
        csr_src[pos] = ((unsigned)pk) >> 7;
    }
}

// ================= layers =================

// register-tiled 64x64 GEMM, bf16 output PREMULTIPLIED by dis[row]:
// outb[r,c] = f2bf(dis[r] * (act(in+b_prev) @ W)[r,c]).  Row n of outb zeroed.
__global__ __launch_bounds__(256) void gemm64_k(
    const float* __restrict__ in, const float* __restrict__ b_prev, int relu_prev,
    const float* __restrict__ W, const float* __restrict__ dis,
    unsigned short* __restrict__ outb, int n)
{
    __shared__ float HsT[HD][68];
    __shared__ float Ws[HD][HD];
    int t = threadIdx.x;
    int rowBase = blockIdx.x * 64;

    for (int i = t; i < HD * HD / 4; i += 256)
        ((float4*)Ws)[i] = ((const float4*)W)[i];

    if (blockIdx.x == 0 && t < 64)   // zero pad-row n (gather target for tails)
        outb[(size_t)n * HD + t] = 0;

    {
        int k0 = (t & 15) * 4;
        float4 bb = make_float4(0.f, 0.f, 0.f, 0.f);
        if (b_prev) bb = *(const float4*)&b_prev[k0];
        for (int it = 0; it < 4; ++it) {
            int r = (t >> 4) + it * 16;
            int row = rowBase + r;
            float4 v = make_float4(0.f, 0.f, 0.f, 0.f);
            if (row < n) {
                v = *(const float4*)&in[(size_t)row * HD + k0];
                v.x += bb.x; v.y += bb.y; v.z += bb.z; v.w += bb.w;
                if (relu_prev) {
                    v.x = fmaxf(v.x, 0.f); v.y = fmaxf(v.y, 0.f);
                    v.z = fmaxf(v.z, 0.f); v.w = fmaxf(v.w, 0.f);
                }
            }
            HsT[k0 + 0][r] = v.x;
            HsT[k0 + 1][r] = v.y;
            HsT[k0 + 2][r] = v.z;
            HsT[k0 + 3][r] = v.w;
        }
    }
    __syncthreads();

    int c4 = (t & 15) * 4;
    int r4 = (t >> 4) * 4;
    float acc[4][4];
    #pragma unroll
    for (int i = 0; i < 4; ++i)
        #pragma unroll
        for (int j = 0; j < 4; ++j) acc[i][j] = 0.f;

    #pragma unroll 8
    for (int k = 0; k < HD; ++k) {
        float4 a = *(const float4*)&HsT[k][r4];
        float4 b = *(const float4*)&Ws[k][c4];
        acc[0][0] += a.x * b.x; acc[0][1] += a.x * b.y; acc[0][2] += a.x * b.z; acc[0][3] += a.x * b.w;
        acc[1][0] += a.y * b.x; acc[1][1] += a.y * b.y; acc[1][2] += a.y * b.z; acc[1][3] += a.y * b.w;
        acc[2][0] += a.z * b.x; acc[2][1] += a.z * b.y; acc[2][2] += a.z * b.z; acc[2][3] += a.z * b.w;
        acc[3][0] += a.w * b.x; acc[3][1] += a.w * b.y; acc[3][2] += a.w * b.z; acc[3][3] += a.w * b.w;
    }

    #pragma unroll
    for (int i = 0; i < 4; ++i) {
        int row = rowBase + r4 + i;
        if (row < n) {
            float ds = dis[row];
            ushort4 o;
            o.x = f2bf(ds * acc[i][0]); o.y = f2bf(ds * acc[i][1]);
            o.z = f2bf(ds * acc[i][2]); o.w = f2bf(ds * acc[i][3]);
            *(ushort4*)&outb[(size_t)row * HD + c4] = o;
        }
    }
}

// Half-feature CSR gather-aggregate, pass p covers cols [32p, 32p+32).
// Per-pass gather working set = 3.2 MB of distinct 64B lines -> L2-resident.
// Lanes 0-31 gather even edges, lanes 32-63 odd edges; cross-half shfl reduce.
// csr_src / agg streams are nontemporal so they don't evict the hot table.
__global__ __launch_bounds__(256) void agg_half_k(const unsigned short* __restrict__ hwb,
    const float* __restrict__ dis, const int* __restrict__ offsets,
    const int* __restrict__ csr_src, float* __restrict__ agg, int n, int p)
{
    int wid  = (blockIdx.x * blockDim.x + threadIdx.x) >> 6;
    int lane = threadIdx.x & 63;
    if (wid >= n) return;
    int f    = lane & 31;
    int half = lane >> 5;
    int col  = (p << 5) + f;

    float acc = half ? 0.f : bf2f(hwb[(size_t)wid * HD + col]);   // self-loop once
    int beg = offsets[wid], end = offsets[wid + 1];

    for (int base = beg; base < end; base += 64) {
        int m = min(64, end - base);
        int idx = (lane < m) ? __builtin_nontemporal_load(csr_src + base + lane) : n;
        for (int j = 0; j < m; j += 16) {
            int rs[8];
            float h[8];
            #pragma unroll
            for (int u = 0; u < 8; ++u) {
                int sA = rdlane(idx, j + 2 * u);
                int sB = rdlane(idx, j + 2 * u + 1);
                rs[u] = half ? sB : sA;
            }
            #pragma unroll
            for (int u = 0; u < 8; ++u)
                h[u] = bf2f(hwb[(size_t)rs[u] * HD + col]);   // 8 paired gathers in flight
            #pragma unroll
            for (int u = 0; u < 8; ++u)
                acc += h[u];
        }
    }
    acc += __shfl_xor(acc, 32, 64);     // combine even/odd edge halves
    if (half == 0)
        __builtin_nontemporal_store(dis[wid] * acc, &agg[(size_t)wid * HD + col]);
}

// Layer-3 half-feature agg fused with pool stage 1 (atomic into partial[g][slot][col]).
__global__ __launch_bounds__(256) void agg_pool_half_k(const unsigned short* __restrict__ hwb,
    const float* __restrict__ dis, const int* __restrict__ offsets,
    const int* __restrict__ csr_src, const int* __restrict__ batch,
    float* __restrict__ partial, int n, int p)
{
    __shared__ float rows[4 * 32];
    __shared__ int   gid[4];
    int t    = threadIdx.x;
    int lane = t & 63;
    int w    = t >> 6;
    int wid  = (blockIdx.x * blockDim.x + t) >> 6;
    int f    = lane & 31;
    int half = lane >> 5;
    int col  = (p << 5) + f;

    float acc = 0.f;
    if (wid < n) {                       // wave-uniform branch (wid uniform per wave)
        acc = half ? 0.f : bf2f(hwb[(size_t)wid * HD + col]);
        int beg = offsets[wid], end = offsets[wid + 1];
        for (int base = beg; base < end; base += 64) {
            int m = min(64, end - base);
            int idx = (lane < m) ? __builtin_nontemporal_load(csr_src + base + lane) : n;
            for (int j = 0; j < m; j += 16) {
                int rs[8];
                float h[8];
                #pragma unroll
                for (int u = 0; u < 8; ++u) {
                    int sA = rdlane(idx, j + 2 * u);
                    int sB = rdlane(idx, j + 2 * u + 1);
                    rs[u] = half ? sB : sA;
                }
                #pragma unroll
                for (int u = 0; u < 8; ++u)
                    h[u] = bf2f(hwb[(size_t)rs[u] * HD + col]);
                #pragma unroll
                for (int u = 0; u < 8; ++u)
                    acc += h[u];
            }
        }
        acc += __shfl_xor(acc, 32, 64);
        acc *= dis[wid];
    }
    if (half == 0) rows[w * 32 + f] = acc;                    // single writer per slot
    if (lane == 0) gid[w] = (wid < n) ? batch[wid] : -1;      // single writer, no race
    __syncthreads();

    if (t < 32) {
        int g0 = gid[0], g1 = gid[1], g2 = gid[2], g3 = gid[3];
        int slot = blockIdx.x & (PSUB - 1);
        int cc = (p << 5) + t;
        if (g0 == g1 && g1 == g2 && g2 == g3 && g0 >= 0) {
            float v = rows[t] + rows[32 + t] + rows[64 + t] + rows[96 + t];
            atomicAdd(&partial[((size_t)g0 * PSUB + slot) * HD + cc], v);
        } else {
            if (g0 >= 0) atomicAdd(&partial[((size_t)g0 * PSUB + slot) * HD + cc], rows[t]);
            if (g1 >= 0) atomicAdd(&partial[((size_t)g1 * PSUB + slot) * HD + cc], rows[32 + t]);
            if (g2 >= 0) atomicAdd(&partial[((size_t)g2 * PSUB + slot) * HD + cc], rows[64 + t]);
            if (g3 >= 0) atomicAdd(&partial[((size_t)g3 * PSUB + slot) * HD + cc], rows[96 + t]);
        }
    }
}

// pooling stage 2: reduce partials, mean + b3, final linear
__global__ __launch_bounds__(64) void pool2_k(const float* __restrict__ partial,
    const int* __restrict__ gstart, const float* __restrict__ b3,
    const float* __restrict__ Wl, const float* __restrict__ bl,
    float* __restrict__ out, int O)
{
    __shared__ float pooled[HD];
    int g = blockIdx.x;
    int t = threadIdx.x;
    float sum = 0.0f;
    #pragma unroll
    for (int s = 0; s < PSUB; ++s)
        sum += partial[((size_t)g * PSUB + s) * HD + t];
    float cnt = (float)(gstart[g + 1] - gstart[g]);
    pooled[t] = sum / cnt + b3[t];
    __syncthreads();
    if (t < O) {
        float acc = bl[t];
        #pragma unroll
        for (int k = 0; k < HD; ++k) acc += pooled[k] * Wl[k * O + t];
        out[g * O + t] = acc;
    }
}

extern "C" void kernel_launch(void* const* d_in, const int* in_sizes, int n_in,
                              void* d_out, int out_size, void* d_ws, size_t ws_size,
                              hipStream_t stream)
{
    const float* x    = (const float*)d_in[0];
    const int*   ei   = (const int*)d_in[1];
    const int*   batch= (const int*)d_in[2];
    const float* W1   = (const float*)d_in[3];
    const float* b1   = (const float*)d_in[4];
    const float* W2   = (const float*)d_in[5];
    const float* b2   = (const float*)d_in[6];
    const float* W3   = (const float*)d_in[7];
    const float* b3   = (const float*)d_in[8];
    const float* Wl   = (const float*)d_in[9];
    const float* bl   = (const float*)d_in[10];
    float* out = (float*)d_out;

    const int N = in_sizes[0] / HD;
    const int E = in_sizes[1] / 2;
    const int O = in_sizes[10];
    const int G = out_size / O;

    const int* src = ei;
    const int* dst = ei + E;

    // ---- workspace layout (256 B aligned) ----
    char* p = (char*)d_ws;
    auto take = [&](size_t bytes) { char* r = p; p += (bytes + 255) & ~(size_t)255; return r; };
    int*   csr_src = (int*)  take((size_t)(E + 256) * 4);  // padded for over-read
    int*   offsets = (int*)  take((size_t)(N + 1) * 4);
    float* dis     = (float*)take((size_t)N * 4);
    int*   gstart  = (int*)  take((size_t)(G + 1) * 4);
    float* partial = (float*)take((size_t)G * PSUB * HD * 4);   // 256 KB
    float* aggF    = (float*)take((size_t)N * HD * 4);          // 12.8 MB
    unsigned short* hwb = (unsigned short*)take((size_t)(N + 1) * HD * 2);  // 6.4 MB (+zero row)

    // aliases into regions not yet live during CSR build:
    int* hist    = (int*)aggF;                 // NBLK*NBKT*4 = 512 KB
    int* scanned = hist + NBLK * NBKT;         // 512 KB
    int* tsum    = scanned + NBLK * NBKT;      // 2 KB
    int* pairs   = (int*)hwb;                  // E*4 = 3.2 MB (packed)

    const int TB = 256;
    int chunk   = (E + NBLK - 1) / NBLK;
    int ntiles  = (NBLK * NBKT) / 256;         // 512
    int nb_gemm = (N + 63) / 64;
    int nb_agg  = (N * 64 + TB - 1) / TB;
    int nbuck   = (N + 127) / 128;
    int psz     = G * PSUB * HD;

    // ---- CSR build (atomic-free counting sort, packed pairs) ----
    hist1_k<<<NBLK, TB, 0, stream>>>(dst, hist, E, chunk);
    scanA_k<<<ntiles, TB, 0, stream>>>(hist, tsum);
    scanB_k<<<1, 1024, 0, stream>>>(tsum, ntiles, batch, gstart, N, G, partial, psz);
    scanC_k<<<ntiles, TB, 0, stream>>>(hist, tsum, scanned);
    append_k<<<NBLK, TB, 0, stream>>>(src, dst, scanned, pairs, E, chunk);
    bucket_csr_k<<<nbuck, TB, 0, stream>>>(pairs, scanned, offsets, dis, csr_src, N, E);

    // ---- layer 1 ----
    gemm64_k<<<nb_gemm, TB, 0, stream>>>(x, nullptr, 0, W1, dis, hwb, N);
    agg_half_k<<<nb_agg, TB, 0, stream>>>(hwb, dis, offsets, csr_src, aggF, N, 0);
    agg_half_k<<<nb_agg, TB, 0, stream>>>(hwb, dis, offsets, csr_src, aggF, N, 1);

    // ---- layer 2 ----
    gemm64_k<<<nb_gemm, TB, 0, stream>>>(aggF, b1, 1, W2, dis, hwb, N);
    agg_half_k<<<nb_agg, TB, 0, stream>>>(hwb, dis, offsets, csr_src, aggF, N, 0);
    agg_half_k<<<nb_agg, TB, 0, stream>>>(hwb, dis, offsets, csr_src, aggF, N, 1);

    // ---- layer 3: gemm, then agg fused with pool stage 1 ----
    gemm64_k<<<nb_gemm, TB, 0, stream>>>(aggF, b2, 1, W3, dis, hwb, N);
    agg_pool_half_k<<<nb_agg, TB, 0, stream>>>(hwb, dis, offsets, csr_src, batch, partial, N, 0);
    agg_pool_half_k<<<nb_agg, TB, 0, stream>>>(hwb, dis, offsets, csr_src, batch, partial, N, 1);

    // ---- pool stage 2 + final linear ----
    pool2_k<<<G, 64, 0, stream>>>(partial, gstart, b3, Wl, bl, out, O);
}

// Round 3
// 209.552 us; speedup vs baseline: 1.4700x; 1.4700x over previous
//
#include <hip/hip_runtime.h>

#define HD 64      // hidden/feature dim (D == H == 64)
#define PSUB 16    // partial slots per graph (pool accumulation spread)
#define NBLK 256   // histogram blocks (edge slices)
#define LOG_NBLK 8
#define NBKT 512   // dst buckets (bucket = dst >> 7, 128 nodes each; N <= 65536)

// ---- bf16 helpers (manual, RNE) ----
__device__ __forceinline__ unsigned short f2bf(float f) {
    union { float f; unsigned u; } v; v.f = f;
    unsigned r = v.u + 0x7FFF + ((v.u >> 16) & 1);
    return (unsigned short)(r >> 16);
}
__device__ __forceinline__ float u2f(unsigned u) {
    union { unsigned u; float f; } v; v.u = u;
    return v.f;
}

// ================= atomic-free bucketed CSR build =================

__global__ __launch_bounds__(256) void hist1_k(const int* __restrict__ dst,
                                               int* __restrict__ hist, int E, int chunk)
{
    __shared__ int lh[NBKT];
    int t = threadIdx.x;
    for (int i = t; i < NBKT; i += 256) lh[i] = 0;
    __syncthreads();
    int base = blockIdx.x * chunk;
    int end  = min(base + chunk, E);
    for (int i = base + t; i < end; i += 256)
        atomicAdd(&lh[dst[i] >> 7], 1);
    __syncthreads();
    for (int i = t; i < NBKT; i += 256)
        hist[blockIdx.x * NBKT + i] = lh[i];
}

// 2a) tile-reduce logical order l = bkt*NBLK + blk  (phys = blk*NBKT + bkt)
__global__ __launch_bounds__(256) void scanA_k(const int* __restrict__ hist,
                                               int* __restrict__ tsum)
{
    __shared__ int s[256];
    int t = threadIdx.x;
    int l = blockIdx.x * 256 + t;
    int phys = (l & (NBLK - 1)) * NBKT + (l >> LOG_NBLK);
    s[t] = hist[phys];
    __syncthreads();
    for (int off = 128; off > 0; off >>= 1) {
        if (t < off) s[t] += s[t + off];
        __syncthreads();
    }
    if (t == 0) tsum[blockIdx.x] = s[0];
}

// 2b) single block: exclusive-scan tsum; compute gstart; zero partial
__global__ __launch_bounds__(1024) void scanB_k(int* __restrict__ tsum, int nb,
    const int* __restrict__ batch, int* __restrict__ gstart, int n, int G,
    float* __restrict__ partial, int psz)
{
    __shared__ int s[1024];
    int t = threadIdx.x;
    int v = (t < nb) ? tsum[t] : 0;
    s[t] = v;
    __syncthreads();
    for (int off = 1; off < 1024; off <<= 1) {
        int u = (t >= off) ? s[t - off] : 0;
        __syncthreads();
        s[t] += u;
        __syncthreads();
    }
    if (t < nb) tsum[t] = s[t] - v;
    if (t <= G) {
        if (t == G) gstart[t] = n;
        else {
            int lo = 0, hi = n;
            while (lo < hi) { int m = (lo + hi) >> 1; if (batch[m] < t) lo = m + 1; else hi = m; }
            gstart[t] = lo;
        }
    }
    for (int i = t; i < psz; i += 1024) partial[i] = 0.f;
}

__global__ __launch_bounds__(256) void scanC_k(const int* __restrict__ hist,
                                               const int* __restrict__ tsum,
                                               int* __restrict__ scanned)
{
    __shared__ int s[256];
    int t = threadIdx.x;
    int l = blockIdx.x * 256 + t;
    int phys = (l & (NBLK - 1)) * NBKT + (l >> LOG_NBLK);
    int own = hist[phys];
    s[t] = own;
    __syncthreads();
    for (int off = 1; off < 256; off <<= 1) {
        int u = (t >= off) ? s[t - off] : 0;
        __syncthreads();
        s[t] += u;
        __syncthreads();
    }
    scanned[l] = tsum[blockIdx.x] + s[t] - own;
}

// 3) bucket-sorted append of packed (src<<7 | dst&127); per-block private ranges
__global__ __launch_bounds__(256) void append_k(const int* __restrict__ src,
    const int* __restrict__ dst, const int* __restrict__ scanned,
    int* __restrict__ pairs, int E, int chunk)
{
    __shared__ int cur[NBKT];
    int t = threadIdx.x;
    int blk = blockIdx.x;
    for (int i = t; i < NBKT; i += 256) cur[i] = scanned[i * NBLK + blk];
    __syncthreads();
    int base = blk * chunk;
    int end  = min(base + chunk, E);
    for (int i = base + t; i < end; i += 256) {
        int s = src[i], d = dst[i];
        int p = atomicAdd(&cur[d >> 7], 1);
        pairs[p] = (s << 7) | (d & 127);
    }
}

// 4) per-bucket: node counts -> offsets/dis, then in-bucket scatter of csr_src
__global__ __launch_bounds__(256) void bucket_csr_k(const int* __restrict__ pairs,
    const int* __restrict__ scanned, int* __restrict__ offsets,
    float* __restrict__ dis, int* __restrict__ csr_src, int N, int E)
{
    __shared__ int cnt[128];
    __shared__ int sc[128];
    __shared__ int cur[128];
    int t = threadIdx.x;
    int b = blockIdx.x;
    int nodeBase = b * 128;
    int nNodes = min(128, N - nodeBase);
    int bBase = scanned[b * NBLK];
    int bEnd  = (b + 1 < NBKT) ? scanned[(b + 1) * NBLK] : E;

    if (t < 128) cnt[t] = 0;
    __syncthreads();
    for (int i = bBase + t; i < bEnd; i += 256)
        atomicAdd(&cnt[pairs[i] & 127], 1);
    __syncthreads();
    int myc = (t < 128) ? cnt[t] : 0;
    if (t < 128) sc[t] = myc;
    __syncthreads();
    for (int off = 1; off < 128; off <<= 1) {
        int u = (t < 128 && t >= off) ? sc[t - off] : 0;
        __syncthreads();
        if (t < 128) sc[t] += u;
        __syncthreads();
    }
    if (t < 128) {
        int excl = sc[t] - myc;
        cur[t] = excl;
        if (t < nNodes) {
            offsets[nodeBase + t] = bBase + excl;
            dis[nodeBase + t] = rsqrtf(1.0f + (float)myc);
        }
    }
    if (t == 0 && b == gridDim.x - 1) offsets[N] = E;
    __syncthreads();
    for (int i = bBase + t; i < bEnd; i += 256) {
        int pk = pairs[i];
        int pos = bBase + atomicAdd(&cur[pk & 127], 1);
        csr_src[pos] = ((unsigned)pk) >> 7;
    }
}

// ================= layers =================

// register-tiled 64x64 GEMM, bf16 output PREMULTIPLIED by dis[row]:
// outb[r,c] = f2bf(dis[r] * (act(in+b_prev) @ W)[r,c]).  Row n of outb zeroed.
__global__ __launch_bounds__(256) void gemm64_k(
    const float* __restrict__ in, const float* __restrict__ b_prev, int relu_prev,
    const float* __restrict__ W, const float* __restrict__ dis,
    unsigned short* __restrict__ outb, int n)
{
    __shared__ float HsT[HD][68];
    __shared__ float Ws[HD][HD];
    int t = threadIdx.x;
    int rowBase = blockIdx.x * 64;

    for (int i = t; i < HD * HD / 4; i += 256)
        ((float4*)Ws)[i] = ((const float4*)W)[i];

    if (blockIdx.x == 0 && t < 64)   // zero pad-row n (gather target for tails)
        outb[(size_t)n * HD + t] = 0;

    {
        int k0 = (t & 15) * 4;
        float4 bb = make_float4(0.f, 0.f, 0.f, 0.f);
        if (b_prev) bb = *(const float4*)&b_prev[k0];
        for (int it = 0; it < 4; ++it) {
            int r = (t >> 4) + it * 16;
            int row = rowBase + r;
            float4 v = make_float4(0.f, 0.f, 0.f, 0.f);
            if (row < n) {
                v = *(const float4*)&in[(size_t)row * HD + k0];
                v.x += bb.x; v.y += bb.y; v.z += bb.z; v.w += bb.w;
                if (relu_prev) {
                    v.x = fmaxf(v.x, 0.f); v.y = fmaxf(v.y, 0.f);
                    v.z = fmaxf(v.z, 0.f); v.w = fmaxf(v.w, 0.f);
                }
            }
            HsT[k0 + 0][r] = v.x;
            HsT[k0 + 1][r] = v.y;
            HsT[k0 + 2][r] = v.z;
            HsT[k0 + 3][r] = v.w;
        }
    }
    __syncthreads();

    int c4 = (t & 15) * 4;
    int r4 = (t >> 4) * 4;
    float acc[4][4];
    #pragma unroll
    for (int i = 0; i < 4; ++i)
        #pragma unroll
        for (int j = 0; j < 4; ++j) acc[i][j] = 0.f;

    #pragma unroll 8
    for (int k = 0; k < HD; ++k) {
        float4 a = *(const float4*)&HsT[k][r4];
        float4 b = *(const float4*)&Ws[k][c4];
        acc[0][0] += a.x * b.x; acc[0][1] += a.x * b.y; acc[0][2] += a.x * b.z; acc[0][3] += a.x * b.w;
        acc[1][0] += a.y * b.x; acc[1][1] += a.y * b.y; acc[1][2] += a.y * b.z; acc[1][3] += a.y * b.w;
        acc[2][0] += a.z * b.x; acc[2][1] += a.z * b.y; acc[2][2] += a.z * b.z; acc[2][3] += a.z * b.w;
        acc[3][0] += a.w * b.x; acc[3][1] += a.w * b.y; acc[3][2] += a.w * b.z; acc[3][3] += a.w * b.w;
    }

    #pragma unroll
    for (int i = 0; i < 4; ++i) {
        int row = rowBase + r4 + i;
        if (row < n) {
            float ds = dis[row];
            ushort4 o;
            o.x = f2bf(ds * acc[i][0]); o.y = f2bf(ds * acc[i][1]);
            o.z = f2bf(ds * acc[i][2]); o.w = f2bf(ds * acc[i][3]);
            *(ushort4*)&outb[(size_t)row * HD + c4] = o;
        }
    }
}

// ---- 4-nodes-per-wave gather core ----
// Wave: 4 sub-groups of 16 lanes; sub-group handles one node, lane owns 4 cols.
// Per 4 edges (one per node): 1 shfl + 1 uint2 (8B) gather + ~8 VALU.
// Returns pre-dis accumulated 4 columns (cols fl*4 .. fl*4+3) incl. self-loop.
__device__ __forceinline__ void gather4(const unsigned short* __restrict__ hwb,
    const int* __restrict__ offsets, const int* __restrict__ csr_src,
    int node, bool act, int n, int sub, int fl,
    float& a0, float& a1, float& a2, float& a3)
{
    int beg = 0, end = 0;
    if (act) { beg = offsets[node]; end = offsets[node + 1]; }
    int deg = end - beg;
    int md = deg;
    md = max(md, __shfl_xor(md, 16, 64));
    md = max(md, __shfl_xor(md, 32, 64));   // max degree over the wave's 4 nodes

    int nodeC = act ? node : n;             // inactive -> zero row
    // self-loop
    uint2 sv = *(const uint2*)(hwb + ((size_t)nodeC << 6) + (fl << 2));
    a0 = u2f(sv.x << 16); a1 = u2f(sv.x & 0xFFFF0000u);
    a2 = u2f(sv.y << 16); a3 = u2f(sv.y & 0xFFFF0000u);

    int base = sub << 4;                    // lane base of my 16-lane group
    for (int jb = 0; jb < md; jb += 16) {
        int e = jb + fl;
        int idxv = (e < deg) ? csr_src[beg + e] : n;   // 16 indices per node
        // batch 1: edges jb+0 .. jb+7
        {
            uint2 g[8];
            #pragma unroll
            for (int j = 0; j < 8; ++j) {
                int row = __shfl(idxv, base + j, 64);
                g[j] = *(const uint2*)(hwb + ((size_t)row << 6) + (fl << 2));
            }
            #pragma unroll
            for (int j = 0; j < 8; ++j) {
                a0 += u2f(g[j].x << 16); a1 += u2f(g[j].x & 0xFFFF0000u);
                a2 += u2f(g[j].y << 16); a3 += u2f(g[j].y & 0xFFFF0000u);
            }
        }
        // batch 2: edges jb+8 .. jb+15 (skip if entirely past max degree)
        if (jb + 8 < md) {
            uint2 g[8];
            #pragma unroll
            for (int j = 0; j < 8; ++j) {
                int row = __shfl(idxv, base + 8 + j, 64);
                g[j] = *(const uint2*)(hwb + ((size_t)row << 6) + (fl << 2));
            }
            #pragma unroll
            for (int j = 0; j < 8; ++j) {
                a0 += u2f(g[j].x << 16); a1 += u2f(g[j].x & 0xFFFF0000u);
                a2 += u2f(g[j].y << 16); a3 += u2f(g[j].y & 0xFFFF0000u);
            }
        }
    }
}

// agg[node] = dis[node] * (self + sum_src h'[src]);  4 nodes per wave.
__global__ __launch_bounds__(256) void agg4_k(const unsigned short* __restrict__ hwb,
    const float* __restrict__ dis, const int* __restrict__ offsets,
    const int* __restrict__ csr_src, float* __restrict__ agg, int n)
{
    int t    = threadIdx.x;
    int lane = t & 63;
    int sub  = lane >> 4;
    int fl   = lane & 15;
    int node = blockIdx.x * 16 + (t >> 6) * 4 + sub;   // 16 nodes per block
    bool act = node < n;

    float a0, a1, a2, a3;
    gather4(hwb, offsets, csr_src, node, act, n, sub, fl, a0, a1, a2, a3);

    if (act) {
        float ds = dis[node];
        *(float4*)&agg[(size_t)node * HD + (fl << 2)] =
            make_float4(a0 * ds, a1 * ds, a2 * ds, a3 * ds);
    }
}

// Layer-3 agg fused with pool stage 1.  16 nodes per block; block-level
// fast path (all 16 nodes same graph -> one atomic per column).
__global__ __launch_bounds__(256) void agg_pool4_k(const unsigned short* __restrict__ hwb,
    const float* __restrict__ dis, const int* __restrict__ offsets,
    const int* __restrict__ csr_src, const int* __restrict__ batch,
    float* __restrict__ partial, int n)
{
    __shared__ float sh[16][68];
    __shared__ int gids[16];
    __shared__ int allsame;
    int t    = threadIdx.x;
    int lane = t & 63;
    int sub  = lane >> 4;
    int fl   = lane & 15;
    int w    = t >> 6;
    int nib  = w * 4 + sub;                 // node-in-block 0..15
    int node = blockIdx.x * 16 + nib;
    bool act = node < n;

    float a0, a1, a2, a3;
    gather4(hwb, offsets, csr_src, node, act, n, sub, fl, a0, a1, a2, a3);

    float ds = act ? dis[node] : 0.f;
    *(float4*)&sh[nib][fl << 2] = make_float4(a0 * ds, a1 * ds, a2 * ds, a3 * ds);
    if (fl == 0) gids[nib] = act ? batch[node] : -1;
    __syncthreads();

    if (t == 0) {
        int g0 = gids[0];
        int ok = (g0 >= 0);
        #pragma unroll
        for (int r = 1; r < 16; ++r) ok &= (gids[r] == g0);
        allsame = ok;
    }
    __syncthreads();

    int slot = blockIdx.x & (PSUB - 1);
    if (allsame) {
        if (t < 64) {
            float s = 0.f;
            #pragma unroll
            for (int r = 0; r < 16; ++r) s += sh[r][t];
            atomicAdd(&partial[((size_t)gids[0] * PSUB + slot) * HD + t], s);
        }
    } else {
        int c  = t & 63;
        int r0 = w * 4;
        int ga = gids[r0], gb = gids[r0 + 1], gc = gids[r0 + 2], gd = gids[r0 + 3];
        if (ga == gb && gb == gc && gc == gd && ga >= 0) {
            float v = sh[r0][c] + sh[r0 + 1][c] + sh[r0 + 2][c] + sh[r0 + 3][c];
            atomicAdd(&partial[((size_t)ga * PSUB + slot) * HD + c], v);
        } else {
            if (ga >= 0) atomicAdd(&partial[((size_t)ga * PSUB + slot) * HD + c], sh[r0][c]);
            if (gb >= 0) atomicAdd(&partial[((size_t)gb * PSUB + slot) * HD + c], sh[r0 + 1][c]);
            if (gc >= 0) atomicAdd(&partial[((size_t)gc * PSUB + slot) * HD + c], sh[r0 + 2][c]);
            if (gd >= 0) atomicAdd(&partial[((size_t)gd * PSUB + slot) * HD + c], sh[r0 + 3][c]);
        }
    }
}

// pooling stage 2: reduce partials, mean + b3, final linear
__global__ __launch_bounds__(64) void pool2_k(const float* __restrict__ partial,
    const int* __restrict__ gstart, const float* __restrict__ b3,
    const float* __restrict__ Wl, const float* __restrict__ bl,
    float* __restrict__ out, int O)
{
    __shared__ float pooled[HD];
    int g = blockIdx.x;
    int t = threadIdx.x;
    float sum = 0.0f;
    #pragma unroll
    for (int s = 0; s < PSUB; ++s)
        sum += partial[((size_t)g * PSUB + s) * HD + t];
    float cnt = (float)(gstart[g + 1] - gstart[g]);
    pooled[t] = sum / cnt + b3[t];
    __syncthreads();
    if (t < O) {
        float acc = bl[t];
        #pragma unroll
        for (int k = 0; k < HD; ++k) acc += pooled[k] * Wl[k * O + t];
        out[g * O + t] = acc;
    }
}

extern "C" void kernel_launch(void* const* d_in, const int* in_sizes, int n_in,
                              void* d_out, int out_size, void* d_ws, size_t ws_size,
                              hipStream_t stream)
{
    const float* x    = (const float*)d_in[0];
    const int*   ei   = (const int*)d_in[1];
    const int*   batch= (const int*)d_in[2];
    const float* W1   = (const float*)d_in[3];
    const float* b1   = (const float*)d_in[4];
    const float* W2   = (const float*)d_in[5];
    const float* b2   = (const float*)d_in[6];
    const float* W3   = (const float*)d_in[7];
    const float* b3   = (const float*)d_in[8];
    const float* Wl   = (const float*)d_in[9];
    const float* bl   = (const float*)d_in[10];
    float* out = (float*)d_out;

    const int N = in_sizes[0] / HD;
    const int E = in_sizes[1] / 2;
    const int O = in_sizes[10];
    const int G = out_size / O;

    const int* src = ei;
    const int* dst = ei + E;

    // ---- workspace layout (256 B aligned) ----
    char* p = (char*)d_ws;
    auto take = [&](size_t bytes) { char* r = p; p += (bytes + 255) & ~(size_t)255; return r; };
    int*   csr_src = (int*)  take((size_t)(E + 256) * 4);  // padded for over-read
    int*   offsets = (int*)  take((size_t)(N + 1) * 4);
    float* dis     = (float*)take((size_t)N * 4);
    int*   gstart  = (int*)  take((size_t)(G + 1) * 4);
    float* partial = (float*)take((size_t)G * PSUB * HD * 4);   // 256 KB
    float* aggF    = (float*)take((size_t)N * HD * 4);          // 12.8 MB
    unsigned short* hwb = (unsigned short*)take((size_t)(N + 1) * HD * 2);  // 6.4 MB (+zero row)

    // aliases into regions not yet live during CSR build:
    int* hist    = (int*)aggF;                 // NBLK*NBKT*4 = 512 KB
    int* scanned = hist + NBLK * NBKT;         // 512 KB
    int* tsum    = scanned + NBLK * NBKT;      // 2 KB
    int* pairs   = (int*)hwb;                  // E*4 = 3.2 MB (packed)

    const int TB = 256;
    int chunk   = (E + NBLK - 1) / NBLK;
    int ntiles  = (NBLK * NBKT) / 256;         // 512
    int nb_gemm = (N + 63) / 64;
    int nb_agg4 = (N + 15) / 16;               // 16 nodes per block (4/wave)
    int nbuck   = (N + 127) / 128;
    int psz     = G * PSUB * HD;

    // ---- CSR build (atomic-free counting sort, packed pairs) ----
    hist1_k<<<NBLK, TB, 0, stream>>>(dst, hist, E, chunk);
    scanA_k<<<ntiles, TB, 0, stream>>>(hist, tsum);
    scanB_k<<<1, 1024, 0, stream>>>(tsum, ntiles, batch, gstart, N, G, partial, psz);
    scanC_k<<<ntiles, TB, 0, stream>>>(hist, tsum, scanned);
    append_k<<<NBLK, TB, 0, stream>>>(src, dst, scanned, pairs, E, chunk);
    bucket_csr_k<<<nbuck, TB, 0, stream>>>(pairs, scanned, offsets, dis, csr_src, N, E);

    // ---- layer 1 ----
    gemm64_k<<<nb_gemm, TB, 0, stream>>>(x, nullptr, 0, W1, dis, hwb, N);
    agg4_k<<<nb_agg4, TB, 0, stream>>>(hwb, dis, offsets, csr_src, aggF, N);

    // ---- layer 2 ----
    gemm64_k<<<nb_gemm, TB, 0, stream>>>(aggF, b1, 1, W2, dis, hwb, N);
    agg4_k<<<nb_agg4, TB, 0, stream>>>(hwb, dis, offsets, csr_src, aggF, N);

    // ---- layer 3: gemm, then agg fused with pool stage 1 ----
    gemm64_k<<<nb_gemm, TB, 0, stream>>>(aggF, b2, 1, W3, dis, hwb, N);
    agg_pool4_k<<<nb_agg4, TB, 0, stream>>>(hwb, dis, offsets, csr_src, batch, partial, N);

    // ---- pool stage 2 + final linear ----
    pool2_k<<<G, 64, 0, stream>>>(partial, gstart, b3, Wl, bl, out, O);
}

// Round 4
// 192.360 us; speedup vs baseline: 1.6014x; 1.0894x over previous
//
#include <hip/hip_runtime.h>

#define HD 64      // hidden/feature dim (D == H == 64)
#define PSUB 16    // partial slots per graph (pool accumulation spread)
#define NBLK 256   // histogram blocks (edge slices)
#define LOG_NBLK 8
#define NBKT 512   // dst buckets (bucket = dst >> 7, 128 nodes each; N <= 65536)

// ---- bf16 helpers (manual, RNE) ----
__device__ __forceinline__ unsigned short f2bf(float f) {
    union { float f; unsigned u; } v; v.f = f;
    unsigned r = v.u + 0x7FFF + ((v.u >> 16) & 1);
    return (unsigned short)(r >> 16);
}
__device__ __forceinline__ float u2f(unsigned u) {
    union { unsigned u; float f; } v; v.u = u;
    return v.f;
}

// ================= atomic-free bucketed CSR build =================

// also zeroes the pool 'partial' buffer (grid-parallel, was serial in scanB)
__global__ __launch_bounds__(256) void hist1_k(const int* __restrict__ dst,
                                               int* __restrict__ hist, int E, int chunk,
                                               float* __restrict__ partial, int psz)
{
    __shared__ int lh[NBKT];
    int t = threadIdx.x;
    for (int i = t; i < NBKT; i += 256) lh[i] = 0;
    for (int i = blockIdx.x * 256 + t; i < psz; i += gridDim.x * 256)
        partial[i] = 0.f;
    __syncthreads();
    int base = blockIdx.x * chunk;
    int end  = min(base + chunk, E);
    for (int i = base + t; i < end; i += 256)
        atomicAdd(&lh[dst[i] >> 7], 1);
    __syncthreads();
    for (int i = t; i < NBKT; i += 256)
        hist[blockIdx.x * NBKT + i] = lh[i];
}

// 2a) tile-reduce logical order l = bkt*NBLK + blk  (phys = blk*NBKT + bkt)
__global__ __launch_bounds__(256) void scanA_k(const int* __restrict__ hist,
                                               int* __restrict__ tsum)
{
    __shared__ int s[256];
    int t = threadIdx.x;
    int l = blockIdx.x * 256 + t;
    int phys = (l & (NBLK - 1)) * NBKT + (l >> LOG_NBLK);
    s[t] = hist[phys];
    __syncthreads();
    for (int off = 128; off > 0; off >>= 1) {
        if (t < off) s[t] += s[t + off];
        __syncthreads();
    }
    if (t == 0) tsum[blockIdx.x] = s[0];
}

// 2b) single block: exclusive-scan tsum; compute gstart
__global__ __launch_bounds__(1024) void scanB_k(int* __restrict__ tsum, int nb,
    const int* __restrict__ batch, int* __restrict__ gstart, int n, int G)
{
    __shared__ int s[1024];
    int t = threadIdx.x;
    int v = (t < nb) ? tsum[t] : 0;
    s[t] = v;
    __syncthreads();
    for (int off = 1; off < 1024; off <<= 1) {
        int u = (t >= off) ? s[t - off] : 0;
        __syncthreads();
        s[t] += u;
        __syncthreads();
    }
    if (t < nb) tsum[t] = s[t] - v;
    if (t <= G) {
        if (t == G) gstart[t] = n;
        else {
            int lo = 0, hi = n;
            while (lo < hi) { int m = (lo + hi) >> 1; if (batch[m] < t) lo = m + 1; else hi = m; }
            gstart[t] = lo;
        }
    }
}

__global__ __launch_bounds__(256) void scanC_k(const int* __restrict__ hist,
                                               const int* __restrict__ tsum,
                                               int* __restrict__ scanned)
{
    __shared__ int s[256];
    int t = threadIdx.x;
    int l = blockIdx.x * 256 + t;
    int phys = (l & (NBLK - 1)) * NBKT + (l >> LOG_NBLK);
    int own = hist[phys];
    s[t] = own;
    __syncthreads();
    for (int off = 1; off < 256; off <<= 1) {
        int u = (t >= off) ? s[t - off] : 0;
        __syncthreads();
        s[t] += u;
        __syncthreads();
    }
    scanned[l] = tsum[blockIdx.x] + s[t] - own;
}

// 3) bucket-sorted append of packed (src<<7 | dst&127); per-block private ranges
__global__ __launch_bounds__(256) void append_k(const int* __restrict__ src,
    const int* __restrict__ dst, const int* __restrict__ scanned,
    int* __restrict__ pairs, int E, int chunk)
{
    __shared__ int cur[NBKT];
    int t = threadIdx.x;
    int blk = blockIdx.x;
    for (int i = t; i < NBKT; i += 256) cur[i] = scanned[i * NBLK + blk];
    __syncthreads();
    int base = blk * chunk;
    int end  = min(base + chunk, E);
    for (int i = base + t; i < end; i += 256) {
        int s = src[i], d = dst[i];
        int p = atomicAdd(&cur[d >> 7], 1);
        pairs[p] = (s << 7) | (d & 127);
    }
}

// 4) per-bucket: node counts -> offsets/dis, then in-bucket scatter of csr_src
__global__ __launch_bounds__(256) void bucket_csr_k(const int* __restrict__ pairs,
    const int* __restrict__ scanned, int* __restrict__ offsets,
    float* __restrict__ dis, int* __restrict__ csr_src, int N, int E)
{
    __shared__ int cnt[128];
    __shared__ int sc[128];
    __shared__ int cur[128];
    int t = threadIdx.x;
    int b = blockIdx.x;
    int nodeBase = b * 128;
    int nNodes = min(128, N - nodeBase);
    int bBase = scanned[b * NBLK];
    int bEnd  = (b + 1 < NBKT) ? scanned[(b + 1) * NBLK] : E;

    if (t < 128) cnt[t] = 0;
    __syncthreads();
    for (int i = bBase + t; i < bEnd; i += 256)
        atomicAdd(&cnt[pairs[i] & 127], 1);
    __syncthreads();
    int myc = (t < 128) ? cnt[t] : 0;
    if (t < 128) sc[t] = myc;
    __syncthreads();
    for (int off = 1; off < 128; off <<= 1) {
        int u = (t < 128 && t >= off) ? sc[t - off] : 0;
        __syncthreads();
        if (t < 128) sc[t] += u;
        __syncthreads();
    }
    if (t < 128) {
        int excl = sc[t] - myc;
        cur[t] = excl;
        if (t < nNodes) {
            offsets[nodeBase + t] = bBase + excl;
            dis[nodeBase + t] = rsqrtf(1.0f + (float)myc);
        }
    }
    if (t == 0 && b == gridDim.x - 1) offsets[N] = E;
    __syncthreads();
    for (int i = bBase + t; i < bEnd; i += 256) {
        int pk = pairs[i];
        int pos = bBase + atomicAdd(&cur[pk & 127], 1);
        csr_src[pos] = ((unsigned)pk) >> 7;
    }
}

// ================= layers =================

// register-tiled 64x64 GEMM, bf16 output PREMULTIPLIED by dis[row]:
// outb[r,c] = f2bf(dis[r] * (act(in+b_prev) @ W)[r,c]).  Row n of outb zeroed.
__global__ __launch_bounds__(256) void gemm64_k(
    const float* __restrict__ in, const float* __restrict__ b_prev, int relu_prev,
    const float* __restrict__ W, const float* __restrict__ dis,
    unsigned short* __restrict__ outb, int n)
{
    __shared__ float HsT[HD][68];
    __shared__ float Ws[HD][HD];
    int t = threadIdx.x;
    int rowBase = blockIdx.x * 64;

    for (int i = t; i < HD * HD / 4; i += 256)
        ((float4*)Ws)[i] = ((const float4*)W)[i];

    if (blockIdx.x == 0 && t < 64)   // zero pad-row n (gather target for tails)
        outb[(size_t)n * HD + t] = 0;

    {
        int k0 = (t & 15) * 4;
        float4 bb = make_float4(0.f, 0.f, 0.f, 0.f);
        if (b_prev) bb = *(const float4*)&b_prev[k0];
        for (int it = 0; it < 4; ++it) {
            int r = (t >> 4) + it * 16;
            int row = rowBase + r;
            float4 v = make_float4(0.f, 0.f, 0.f, 0.f);
            if (row < n) {
                v = *(const float4*)&in[(size_t)row * HD + k0];
                v.x += bb.x; v.y += bb.y; v.z += bb.z; v.w += bb.w;
                if (relu_prev) {
                    v.x = fmaxf(v.x, 0.f); v.y = fmaxf(v.y, 0.f);
                    v.z = fmaxf(v.z, 0.f); v.w = fmaxf(v.w, 0.f);
                }
            }
            HsT[k0 + 0][r] = v.x;
            HsT[k0 + 1][r] = v.y;
            HsT[k0 + 2][r] = v.z;
            HsT[k0 + 3][r] = v.w;
        }
    }
    __syncthreads();

    int c4 = (t & 15) * 4;
    int r4 = (t >> 4) * 4;
    float acc[4][4];
    #pragma unroll
    for (int i = 0; i < 4; ++i)
        #pragma unroll
        for (int j = 0; j < 4; ++j) acc[i][j] = 0.f;

    #pragma unroll 8
    for (int k = 0; k < HD; ++k) {
        float4 a = *(const float4*)&HsT[k][r4];
        float4 b = *(const float4*)&Ws[k][c4];
        acc[0][0] += a.x * b.x; acc[0][1] += a.x * b.y; acc[0][2] += a.x * b.z; acc[0][3] += a.x * b.w;
        acc[1][0] += a.y * b.x; acc[1][1] += a.y * b.y; acc[1][2] += a.y * b.z; acc[1][3] += a.y * b.w;
        acc[2][0] += a.z * b.x; acc[2][1] += a.z * b.y; acc[2][2] += a.z * b.z; acc[2][3] += a.z * b.w;
        acc[3][0] += a.w * b.x; acc[3][1] += a.w * b.y; acc[3][2] += a.w * b.z; acc[3][3] += a.w * b.w;
    }

    #pragma unroll
    for (int i = 0; i < 4; ++i) {
        int row = rowBase + r4 + i;
        if (row < n) {
            float ds = dis[row];
            ushort4 o;
            o.x = f2bf(ds * acc[i][0]); o.y = f2bf(ds * acc[i][1]);
            o.z = f2bf(ds * acc[i][2]); o.w = f2bf(ds * acc[i][3]);
            *(ushort4*)&outb[(size_t)row * HD + c4] = o;
        }
    }
}

// ---- 4-nodes-per-wave gather core (unchanged from round 3) ----
// Wave: 4 sub-groups of 16 lanes; sub-group handles one node, lane owns 4 cols.
// Per 4 edges (one per node): 1 shfl + 1 uint2 (8B) gather + ~8 VALU.
// Returns pre-dis accumulated 4 columns (cols fl*4 .. fl*4+3) incl. self-loop.
__device__ __forceinline__ void gather4(const unsigned short* __restrict__ hwb,
    const int* __restrict__ offsets, const int* __restrict__ csr_src,
    int node, bool act, int n, int sub, int fl,
    float& a0, float& a1, float& a2, float& a3)
{
    int beg = 0, end = 0;
    if (act) { beg = offsets[node]; end = offsets[node + 1]; }
    int deg = end - beg;
    int md = deg;
    md = max(md, __shfl_xor(md, 16, 64));
    md = max(md, __shfl_xor(md, 32, 64));   // max degree over the wave's 4 nodes

    int nodeC = act ? node : n;             // inactive -> zero row
    // self-loop
    uint2 sv = *(const uint2*)(hwb + ((size_t)nodeC << 6) + (fl << 2));
    a0 = u2f(sv.x << 16); a1 = u2f(sv.x & 0xFFFF0000u);
    a2 = u2f(sv.y << 16); a3 = u2f(sv.y & 0xFFFF0000u);

    int base = sub << 4;                    // lane base of my 16-lane group
    for (int jb = 0; jb < md; jb += 16) {
        int e = jb + fl;
        int idxv = (e < deg) ? csr_src[beg + e] : n;   // 16 indices per node
        // batch 1: edges jb+0 .. jb+7
        {
            uint2 g[8];
            #pragma unroll
            for (int j = 0; j < 8; ++j) {
                int row = __shfl(idxv, base + j, 64);
                g[j] = *(const uint2*)(hwb + ((size_t)row << 6) + (fl << 2));
            }
            #pragma unroll
            for (int j = 0; j < 8; ++j) {
                a0 += u2f(g[j].x << 16); a1 += u2f(g[j].x & 0xFFFF0000u);
                a2 += u2f(g[j].y << 16); a3 += u2f(g[j].y & 0xFFFF0000u);
            }
        }
        // batch 2: edges jb+8 .. jb+15 (skip if entirely past max degree)
        if (jb + 8 < md) {
            uint2 g[8];
            #pragma unroll
            for (int j = 0; j < 8; ++j) {
                int row = __shfl(idxv, base + 8 + j, 64);
                g[j] = *(const uint2*)(hwb + ((size_t)row << 6) + (fl << 2));
            }
            #pragma unroll
            for (int j = 0; j < 8; ++j) {
                a0 += u2f(g[j].x << 16); a1 += u2f(g[j].x & 0xFFFF0000u);
                a2 += u2f(g[j].y << 16); a3 += u2f(g[j].y & 0xFFFF0000u);
            }
        }
    }
}

// Fused {agg_l -> relu(+b) -> GEMM W_{l+1} -> *dis -> bf16 table}.
// Block = 256 threads = 4 waves = 16 nodes.  Gather identical to agg4;
// activation tile staged in LDS, 16x64 GEMM, output ping-pongs tables.
__global__ __launch_bounds__(256) void agg_gemm_k(
    const unsigned short* __restrict__ hwb, const float* __restrict__ dis,
    const int* __restrict__ offsets, const int* __restrict__ csr_src,
    const float* __restrict__ b_prev, const float* __restrict__ W,
    unsigned short* __restrict__ outb, int n)
{
    __shared__ float As[16][68];
    __shared__ float Ws[HD][HD];
    int t    = threadIdx.x;
    int lane = t & 63;
    int sub  = lane >> 4;
    int fl   = lane & 15;
    int w    = t >> 6;
    int nib  = w * 4 + sub;
    int nodeBase = blockIdx.x * 16;
    int node = nodeBase + nib;
    bool act = node < n;

    for (int i = t; i < HD * HD / 4; i += 256)
        ((float4*)Ws)[i] = ((const float4*)W)[i];

    if (blockIdx.x == 0 && t < 64)   // zero pad-row n of OUTPUT table
        outb[(size_t)n * HD + t] = 0;

    float a0, a1, a2, a3;
    gather4(hwb, offsets, csr_src, node, act, n, sub, fl, a0, a1, a2, a3);

    float ds = act ? dis[node] : 0.f;
    int c0 = fl << 2;
    float4 bb = *(const float4*)&b_prev[c0];
    float4 v;
    v.x = fmaxf(a0 * ds + bb.x, 0.f);
    v.y = fmaxf(a1 * ds + bb.y, 0.f);
    v.z = fmaxf(a2 * ds + bb.z, 0.f);
    v.w = fmaxf(a3 * ds + bb.w, 0.f);
    *(float4*)&As[nib][c0] = v;
    __syncthreads();

    // GEMM: 16 rows x 64 cols; thread -> (r = t&15, c4 = (t>>4)*4)
    int r  = t & 15;
    int c4 = (t >> 4) << 2;
    float acc0 = 0.f, acc1 = 0.f, acc2 = 0.f, acc3 = 0.f;
    #pragma unroll 4
    for (int k = 0; k < HD; k += 4) {
        float4 a  = *(const float4*)&As[r][k];
        float4 w0 = *(const float4*)&Ws[k + 0][c4];
        float4 w1 = *(const float4*)&Ws[k + 1][c4];
        float4 w2 = *(const float4*)&Ws[k + 2][c4];
        float4 w3 = *(const float4*)&Ws[k + 3][c4];
        acc0 += a.x * w0.x + a.y * w1.x + a.z * w2.x + a.w * w3.x;
        acc1 += a.x * w0.y + a.y * w1.y + a.z * w2.y + a.w * w3.y;
        acc2 += a.x * w0.z + a.y * w1.z + a.z * w2.z + a.w * w3.z;
        acc3 += a.x * w0.w + a.y * w1.w + a.z * w2.w + a.w * w3.w;
    }
    int orow = nodeBase + r;
    if (orow < n) {
        float d2 = dis[orow];
        ushort4 o;
        o.x = f2bf(d2 * acc0); o.y = f2bf(d2 * acc1);
        o.z = f2bf(d2 * acc2); o.w = f2bf(d2 * acc3);
        *(ushort4*)&outb[(size_t)orow * HD + c4] = o;
    }
}

// Layer-3 agg fused with pool stage 1.  16 nodes per block; block-level
// fast path (all 16 nodes same graph -> one atomic per column).
__global__ __launch_bounds__(256) void agg_pool4_k(const unsigned short* __restrict__ hwb,
    const float* __restrict__ dis, const int* __restrict__ offsets,
    const int* __restrict__ csr_src, const int* __restrict__ batch,
    float* __restrict__ partial, int n)
{
    __shared__ float sh[16][68];
    __shared__ int gids[16];
    __shared__ int allsame;
    int t    = threadIdx.x;
    int lane = t & 63;
    int sub  = lane >> 4;
    int fl   = lane & 15;
    int w    = t >> 6;
    int nib  = w * 4 + sub;                 // node-in-block 0..15
    int node = blockIdx.x * 16 + nib;
    bool act = node < n;

    float a0, a1, a2, a3;
    gather4(hwb, offsets, csr_src, node, act, n, sub, fl, a0, a1, a2, a3);

    float ds = act ? dis[node] : 0.f;
    *(float4*)&sh[nib][fl << 2] = make_float4(a0 * ds, a1 * ds, a2 * ds, a3 * ds);
    if (fl == 0) gids[nib] = act ? batch[node] : -1;
    __syncthreads();

    if (t == 0) {
        int g0 = gids[0];
        int ok = (g0 >= 0);
        #pragma unroll
        for (int r = 1; r < 16; ++r) ok &= (gids[r] == g0);
        allsame = ok;
    }
    __syncthreads();

    int slot = blockIdx.x & (PSUB - 1);
    if (allsame) {
        if (t < 64) {
            float s = 0.f;
            #pragma unroll
            for (int r = 0; r < 16; ++r) s += sh[r][t];
            atomicAdd(&partial[((size_t)gids[0] * PSUB + slot) * HD + t], s);
        }
    } else {
        int c  = t & 63;
        int r0 = w * 4;
        int ga = gids[r0], gb = gids[r0 + 1], gc = gids[r0 + 2], gd = gids[r0 + 3];
        if (ga == gb && gb == gc && gc == gd && ga >= 0) {
            float v = sh[r0][c] + sh[r0 + 1][c] + sh[r0 + 2][c] + sh[r0 + 3][c];
            atomicAdd(&partial[((size_t)ga * PSUB + slot) * HD + c], v);
        } else {
            if (ga >= 0) atomicAdd(&partial[((size_t)ga * PSUB + slot) * HD + c], sh[r0][c]);
            if (gb >= 0) atomicAdd(&partial[((size_t)gb * PSUB + slot) * HD + c], sh[r0 + 1][c]);
            if (gc >= 0) atomicAdd(&partial[((size_t)gc * PSUB + slot) * HD + c], sh[r0 + 2][c]);
            if (gd >= 0) atomicAdd(&partial[((size_t)gd * PSUB + slot) * HD + c], sh[r0 + 3][c]);
        }
    }
}

// pooling stage 2: reduce partials, mean + b3, final linear
__global__ __launch_bounds__(64) void pool2_k(const float* __restrict__ partial,
    const int* __restrict__ gstart, const float* __restrict__ b3,
    const float* __restrict__ Wl, const float* __restrict__ bl,
    float* __restrict__ out, int O)
{
    __shared__ float pooled[HD];
    int g = blockIdx.x;
    int t = threadIdx.x;
    float sum = 0.0f;
    #pragma unroll
    for (int s = 0; s < PSUB; ++s)
        sum += partial[((size_t)g * PSUB + s) * HD + t];
    float cnt = (float)(gstart[g + 1] - gstart[g]);
    pooled[t] = sum / cnt + b3[t];
    __syncthreads();
    if (t < O) {
        float acc = bl[t];
        #pragma unroll
        for (int k = 0; k < HD; ++k) acc += pooled[k] * Wl[k * O + t];
        out[g * O + t] = acc;
    }
}

extern "C" void kernel_launch(void* const* d_in, const int* in_sizes, int n_in,
                              void* d_out, int out_size, void* d_ws, size_t ws_size,
                              hipStream_t stream)
{
    const float* x    = (const float*)d_in[0];
    const int*   ei   = (const int*)d_in[1];
    const int*   batch= (const int*)d_in[2];
    const float* W1   = (const float*)d_in[3];
    const float* b1   = (const float*)d_in[4];
    const float* W2   = (const float*)d_in[5];
    const float* b2   = (const float*)d_in[6];
    const float* W3   = (const float*)d_in[7];
    const float* b3   = (const float*)d_in[8];
    const float* Wl   = (const float*)d_in[9];
    const float* bl   = (const float*)d_in[10];
    float* out = (float*)d_out;

    const int N = in_sizes[0] / HD;
    const int E = in_sizes[1] / 2;
    const int O = in_sizes[10];
    const int G = out_size / O;

    const int* src = ei;
    const int* dst = ei + E;

    // ---- workspace layout (256 B aligned) ----
    char* p = (char*)d_ws;
    auto take = [&](size_t bytes) { char* r = p; p += (bytes + 255) & ~(size_t)255; return r; };
    int*   csr_src = (int*)  take((size_t)(E + 256) * 4);  // padded for over-read
    int*   offsets = (int*)  take((size_t)(N + 1) * 4);
    float* dis     = (float*)take((size_t)N * 4);
    int*   gstart  = (int*)  take((size_t)(G + 1) * 4);
    float* partial = (float*)take((size_t)G * PSUB * HD * 4);           // 256 KB
    unsigned short* hwb  = (unsigned short*)take((size_t)(N + 1) * HD * 2);  // 6.4 MB (+zero row)
    unsigned short* hwb2 = (unsigned short*)take((size_t)(N + 1) * HD * 2);  // 6.4 MB (+zero row)

    // aliases into regions not yet live during CSR build:
    int* pairs   = (int*)hwb;                  // E*4 = 3.2 MB (packed)
    int* hist    = (int*)hwb2;                 // NBLK*NBKT*4 = 512 KB
    int* scanned = hist + NBLK * NBKT;         // 512 KB
    int* tsum    = scanned + NBLK * NBKT;      // 2 KB

    const int TB = 256;
    int chunk   = (E + NBLK - 1) / NBLK;
    int ntiles  = (NBLK * NBKT) / 256;         // 512
    int nb_gemm = (N + 63) / 64;
    int nb_agg4 = (N + 15) / 16;               // 16 nodes per block (4/wave)
    int nbuck   = (N + 127) / 128;
    int psz     = G * PSUB * HD;

    // ---- CSR build (atomic-free counting sort, packed pairs) ----
    hist1_k<<<NBLK, TB, 0, stream>>>(dst, hist, E, chunk, partial, psz);
    scanA_k<<<ntiles, TB, 0, stream>>>(hist, tsum);
    scanB_k<<<1, 1024, 0, stream>>>(tsum, ntiles, batch, gstart, N, G);
    scanC_k<<<ntiles, TB, 0, stream>>>(hist, tsum, scanned);
    append_k<<<NBLK, TB, 0, stream>>>(src, dst, scanned, pairs, E, chunk);
    bucket_csr_k<<<nbuck, TB, 0, stream>>>(pairs, scanned, offsets, dis, csr_src, N, E);

    // ---- layer 1: x @ W1 -> dis-premult bf16 table ----
    gemm64_k<<<nb_gemm, TB, 0, stream>>>(x, nullptr, 0, W1, dis, hwb, N);

    // ---- layer 2 fused: agg(hwb) -> relu(+b1) -> @W2 -> hwb2 ----
    agg_gemm_k<<<nb_agg4, TB, 0, stream>>>(hwb, dis, offsets, csr_src, b1, W2, hwb2, N);

    // ---- layer 3 fused: agg(hwb2) -> relu(+b2) -> @W3 -> hwb ----
    agg_gemm_k<<<nb_agg4, TB, 0, stream>>>(hwb2, dis, offsets, csr_src, b2, W3, hwb, N);

    // ---- final agg fused with pool stage 1 ----
    agg_pool4_k<<<nb_agg4, TB, 0, stream>>>(hwb, dis, offsets, csr_src, batch, partial, N);

    // ---- pool stage 2 + final linear ----
    pool2_k<<<G, 64, 0, stream>>>(partial, gstart, b3, Wl, bl, out, O);
}